// Round 8
// baseline (34.070 us; speedup 1.0000x reference)
//
#include <hip/hip_runtime.h>

// BidPrefix: per row of inputs[B, 302]:
//   rates = row[0:300]; bid = (int)row[300]; mp = (int)row[301]
//   cpz[k] = prod(rates[0:k]); out[row] = { cpz[bid], cpz[mp+1], cpz[mp] }
//
// ZERO-LDS, EXEC-MASKED-SKIP version. One wave64 per 4 rows; 300 = 75*4 so
// a 4-floats-per-lane layout needs no re-layout:
//   chunk A: cols [0,256)   -> lane l owns float4 [4l, 4l+4)
//   chunk B: cols [256,300) -> lane l owns float4 [256+4l,..), lanes 0..10
// Tail-skip via EXEC MASK (R7 insight): lanes whose float4 lies beyond
// maxidx = max(bid, mp+1) issue NO load at all (vs R6's address-clamp which
// still issued a request per skipped lane). Masked lanes keep 0.0 garbage,
// which propagates only UPWARD in the scan; every queried lane (<= idx/4)
// is fully loaded, and totalA is only used when idx >= 256 => mx >= 256 =>
// all A-lanes loaded. Scan: lane-local 4-elem prefixes + 6-step DPP
// multiplicative scan (VALU pipe, zero DS traffic); wave-uniform queries
// via v_readlane. No LDS, no __syncthreads, no ds_* at all.

constexpr int SEQ  = 300;
constexpr int NCOL = 302;
constexpr int RPW  = 4;                // rows per wave
constexpr int WPB  = 4;                // waves per block

template <int CTRL, int ROW_MASK>
__device__ __forceinline__ float mul_scan_step(float run) {
    // DPP-move 'run'; lanes with no valid source (or masked rows) get 1.0
    const int t = __builtin_amdgcn_update_dpp(
        __float_as_int(1.0f), __float_as_int(run), CTRL, ROW_MASK, 0xf, false);
    return run * __int_as_float(t);
}

__global__ __launch_bounds__(256) void bidprefix_kernel(
    const float* __restrict__ in, float* __restrict__ out, int batch)
{
    const int lane = threadIdx.x & 63;
    const int wid  = threadIdx.x >> 6;
    const int row0 = (blockIdx.x * WPB + wid) * RPW;
    if (row0 >= batch) return;

    const float* g = in + (size_t)row0 * NCOL;

    // ---- Phase 1: one dwordx2 covers all 4 rows' (bid,mp) ----
    const float2 bmv = *reinterpret_cast<const float2*>(g + (lane & 3) * NCOL + SEQ);
    const int ibv = (int)bmv.x;
    const int imv = (int)bmv.y;
    int bid[RPW], mp[RPW], mx[RPW];
    #pragma unroll
    for (int r = 0; r < RPW; ++r) {
        bid[r] = __builtin_amdgcn_readlane(ibv, r);
        mp[r]  = __builtin_amdgcn_readlane(imv, r);
        mx[r]  = max(bid[r], mp[r] + 1);     // #rates needed (<= 300)
    }

    // ---- Phase 2: exec-masked bulk loads, all in flight together ----
    float4 A[RPW], B[RPW];
    const int fa = 4 * lane;                 // chunk-A cols [4l, 4l+4)
    const int fb = 256 + 4 * lane;           // chunk-B cols, lanes 0..10
    #pragma unroll
    for (int r = 0; r < RPW; ++r) {
        const float* gr = g + r * NCOL;
        A[r] = make_float4(0.f, 0.f, 0.f, 0.f);
        B[r] = make_float4(0.f, 0.f, 0.f, 0.f);
        if (fa < mx[r]) A[r] = *reinterpret_cast<const float4*>(gr + fa);
        if (fb < mx[r]) B[r] = *reinterpret_cast<const float4*>(gr + fb);
    }

    // ---- Phase 3: per-row DPP scans + scalar gathers + store ----
    #pragma unroll
    for (int r = 0; r < RPW; ++r) {
        // chunk A: lane-local prefixes + 64-lane multiplicative scan
        const float pa1 = A[r].x;
        const float pa2 = pa1 * A[r].y;
        const float pa3 = pa2 * A[r].z;
        const float pa4 = pa3 * A[r].w;
        float runA = pa4;
        runA = mul_scan_step<0x111, 0xf>(runA);   // row_shr:1
        runA = mul_scan_step<0x112, 0xf>(runA);   // row_shr:2
        runA = mul_scan_step<0x114, 0xf>(runA);   // row_shr:4
        runA = mul_scan_step<0x118, 0xf>(runA);   // row_shr:8
        runA = mul_scan_step<0x142, 0xa>(runA);   // row_bcast15 -> rows 1,3
        runA = mul_scan_step<0x143, 0xc>(runA);   // row_bcast31 -> rows 2,3
        const float totalA = __int_as_float(
            __builtin_amdgcn_readlane(__float_as_int(runA), 63));

        // chunk B: lanes 0..10, single DPP row -> 4 row_shr steps suffice
        const float pb1 = B[r].x;
        const float pb2 = pb1 * B[r].y;
        const float pb3 = pb2 * B[r].z;
        const float pb4 = pb3 * B[r].w;
        float runB = pb4;
        runB = mul_scan_step<0x111, 0xf>(runB);   // row_shr:1
        runB = mul_scan_step<0x112, 0xf>(runB);   // row_shr:2
        runB = mul_scan_step<0x114, 0xf>(runB);   // row_shr:4
        runB = mul_scan_step<0x118, 0xf>(runB);   // row_shr:8

        const int idxs[3] = { bid[r], mp[r] + 1, mp[r] };
        float o[3];
        #pragma unroll
        for (int j = 0; j < 3; ++j) {
            const int idx = idxs[j];               // wave-uniform (SGPR)
            float res;
            if (idx < 256) {
                const int bq = idx >> 2;
                const int rm = idx & 3;
                const float qsel = (rm == 0) ? 1.f
                                 : (rm == 1) ? pa1
                                 : (rm == 2) ? pa2
                                 :             pa3;
                const float seg = __int_as_float(
                    __builtin_amdgcn_readlane(__float_as_int(qsel), bq));
                const float pre = (bq > 0)
                    ? __int_as_float(__builtin_amdgcn_readlane(
                          __float_as_int(runA), bq - 1))
                    : 1.f;
                res = pre * seg;
            } else {
                const int t  = idx - 256;
                const int bq = t >> 2;              // 0..11
                const int rm = t & 3;
                const float qsel = (rm == 0) ? 1.f
                                 : (rm == 1) ? pb1
                                 : (rm == 2) ? pb2
                                 :             pb3;
                const float seg = __int_as_float(
                    __builtin_amdgcn_readlane(__float_as_int(qsel), bq));
                const float pre = (bq > 0)
                    ? __int_as_float(__builtin_amdgcn_readlane(
                          __float_as_int(runB), bq - 1))
                    : 1.f;
                res = totalA * pre * seg;
            }
            o[j] = res;                             // cpz[idx]
        }

        if (lane < 3) {
            const float ov = (lane == 0) ? o[0] : (lane == 1) ? o[1] : o[2];
            out[(size_t)(row0 + r) * 3 + lane] = ov;
        }
    }
}

extern "C" void kernel_launch(void* const* d_in, const int* in_sizes, int n_in,
                              void* d_out, int out_size, void* d_ws, size_t ws_size,
                              hipStream_t stream) {
    const float* in = (const float*)d_in[0];
    float* out      = (float*)d_out;
    const int batch = in_sizes[0] / NCOL;             // 200000

    const int rows_per_block = WPB * RPW;             // 16
    dim3 block(256);
    dim3 grid((batch + rows_per_block - 1) / rows_per_block);
    bidprefix_kernel<<<grid, block, 0, stream>>>(in, out, batch);
}

// Round 9
// 33.321 us; speedup vs baseline: 1.0225x; 1.0225x over previous
//
#include <hip/hip_runtime.h>

// BidPrefix: per row of inputs[B, 302]:
//   rates = row[0:300]; bid = (int)row[300]; mp = (int)row[301]
//   cpz[k] = prod(rates[0:k]); out[row] = { cpz[bid], cpz[mp+1], cpz[mp] }
//
// FINAL (= R6, best measured: 33.35 us; holey-stream DRAM roofline).
// ZERO-LDS version. One wave64 per 4 rows. 300 = 75*4, so a 4-floats-per-
// lane layout needs no re-layout at all:
//   chunk A: cols [0,256)   -> lane l owns float4 [4l, 4l+4)   (64 lanes)
//   chunk B: cols [256,300) -> lane l owns float4 [256+4l, ..) (lanes 0..10)
// Both loads are perfectly coalesced (lane-stride == 16B). Tail-skip via
// ADDRESS CLAMP (R7 proved exec-masking is not better): lanes whose float4
// lies fully beyond maxidx = max(bid, mp+1) clamp their address to the row
// start (L1-resident line, no extra HBM traffic). Garbage in skipped/idle
// lanes propagates only UPWARD in the scan; every queried lane (<= idx/4)
// is clean, and queries with idx >= 256 imply maxidx >= 256 so totalA is
// clean too.
// Scan: lane-local 4-elem prefixes + 6-step DPP multiplicative scan (VALU
// pipe) for A; 4-step DPP scan for B (11 lanes, single DPP row). Queries are
// wave-uniform -> scalar b = idx>>2, rm = idx&3, gathers via v_readlane.
// No LDS, no __syncthreads, no ds_* at all.
//
// Roofline accounting (measured):
//   clean full read: 244.6 MB / 41.35 us = 5.92 TB/s (= 6.29 TB/s copy
//   ceiling x 16/17 line-straddle tax of the 1208 B row period).
//   skip fetches ~174 MB; holey-stream burst efficiency ~0.88 ->
//   174 / (5.92*0.88) = 33.4 us predicted vs 33.35 us observed.

constexpr int SEQ  = 300;
constexpr int NCOL = 302;
constexpr int RPW  = 4;                // rows per wave
constexpr int WPB  = 4;                // waves per block

template <int CTRL, int ROW_MASK>
__device__ __forceinline__ float mul_scan_step(float run) {
    // DPP-move 'run'; lanes with no valid source (or masked rows) get 1.0
    const int t = __builtin_amdgcn_update_dpp(
        __float_as_int(1.0f), __float_as_int(run), CTRL, ROW_MASK, 0xf, false);
    return run * __int_as_float(t);
}

__global__ __launch_bounds__(256) void bidprefix_kernel(
    const float* __restrict__ in, float* __restrict__ out, int batch)
{
    const int lane = threadIdx.x & 63;
    const int wid  = threadIdx.x >> 6;
    const int row0 = (blockIdx.x * WPB + wid) * RPW;
    if (row0 >= batch) return;

    const float* g = in + (size_t)row0 * NCOL;

    // ---- Phase 1: one dwordx2 covers all 4 rows' (bid,mp) ----
    const float2 bmv = *reinterpret_cast<const float2*>(g + (lane & 3) * NCOL + SEQ);
    const int ibv = (int)bmv.x;
    const int imv = (int)bmv.y;
    int bid[RPW], mp[RPW], mx[RPW];
    #pragma unroll
    for (int r = 0; r < RPW; ++r) {
        bid[r] = __builtin_amdgcn_readlane(ibv, r);
        mp[r]  = __builtin_amdgcn_readlane(imv, r);
        mx[r]  = max(bid[r], mp[r] + 1);     // #rates needed (<= 300)
    }

    // ---- Phase 2: all 8 bulk loads in flight together (skip-clamped) ----
    float4 A[RPW], B[RPW];
    #pragma unroll
    for (int r = 0; r < RPW; ++r) {
        const float* gr = g + r * NCOL;
        const int fa = 4 * lane;                       // cols [4l, 4l+4)
        A[r] = *reinterpret_cast<const float4*>(gr + ((fa < mx[r]) ? fa : 0));
        const int fb = 256 + 4 * lane;                 // lanes 0..10 useful
        const bool nb = (lane < 11) && (fb < mx[r]);
        B[r] = *reinterpret_cast<const float4*>(gr + (nb ? fb : 0));
    }

    // ---- Phase 3: per-row DPP scans + scalar gathers + store ----
    #pragma unroll
    for (int r = 0; r < RPW; ++r) {
        // chunk A: lane-local prefixes + 64-lane multiplicative scan
        const float pa1 = A[r].x;
        const float pa2 = pa1 * A[r].y;
        const float pa3 = pa2 * A[r].z;
        const float pa4 = pa3 * A[r].w;
        float runA = pa4;
        runA = mul_scan_step<0x111, 0xf>(runA);   // row_shr:1
        runA = mul_scan_step<0x112, 0xf>(runA);   // row_shr:2
        runA = mul_scan_step<0x114, 0xf>(runA);   // row_shr:4
        runA = mul_scan_step<0x118, 0xf>(runA);   // row_shr:8
        runA = mul_scan_step<0x142, 0xa>(runA);   // row_bcast15 -> rows 1,3
        runA = mul_scan_step<0x143, 0xc>(runA);   // row_bcast31 -> rows 2,3
        const float totalA = __int_as_float(
            __builtin_amdgcn_readlane(__float_as_int(runA), 63));

        // chunk B: lanes 0..10, single DPP row -> 4 row_shr steps suffice
        const float pb1 = B[r].x;
        const float pb2 = pb1 * B[r].y;
        const float pb3 = pb2 * B[r].z;
        const float pb4 = pb3 * B[r].w;
        float runB = pb4;
        runB = mul_scan_step<0x111, 0xf>(runB);   // row_shr:1
        runB = mul_scan_step<0x112, 0xf>(runB);   // row_shr:2
        runB = mul_scan_step<0x114, 0xf>(runB);   // row_shr:4
        runB = mul_scan_step<0x118, 0xf>(runB);   // row_shr:8

        const int idxs[3] = { bid[r], mp[r] + 1, mp[r] };
        float o[3];
        #pragma unroll
        for (int j = 0; j < 3; ++j) {
            const int idx = idxs[j];               // wave-uniform (SGPR)
            float res;
            if (idx < 256) {
                const int bq = idx >> 2;
                const int rm = idx & 3;
                const float qsel = (rm == 0) ? 1.f
                                 : (rm == 1) ? pa1
                                 : (rm == 2) ? pa2
                                 :             pa3;
                const float seg = __int_as_float(
                    __builtin_amdgcn_readlane(__float_as_int(qsel), bq));
                const float pre = (bq > 0)
                    ? __int_as_float(__builtin_amdgcn_readlane(
                          __float_as_int(runA), bq - 1))
                    : 1.f;
                res = pre * seg;
            } else {
                const int t  = idx - 256;
                const int bq = t >> 2;              // 0..11
                const int rm = t & 3;
                const float qsel = (rm == 0) ? 1.f
                                 : (rm == 1) ? pb1
                                 : (rm == 2) ? pb2
                                 :             pb3;
                const float seg = __int_as_float(
                    __builtin_amdgcn_readlane(__float_as_int(qsel), bq));
                const float pre = (bq > 0)
                    ? __int_as_float(__builtin_amdgcn_readlane(
                          __float_as_int(runB), bq - 1))
                    : 1.f;
                res = totalA * pre * seg;
            }
            o[j] = res;                             // cpz[idx]
        }

        if (lane < 3) {
            const float ov = (lane == 0) ? o[0] : (lane == 1) ? o[1] : o[2];
            out[(size_t)(row0 + r) * 3 + lane] = ov;
        }
    }
}

extern "C" void kernel_launch(void* const* d_in, const int* in_sizes, int n_in,
                              void* d_out, int out_size, void* d_ws, size_t ws_size,
                              hipStream_t stream) {
    const float* in = (const float*)d_in[0];
    float* out      = (float*)d_out;
    const int batch = in_sizes[0] / NCOL;             // 200000

    const int rows_per_block = WPB * RPW;             // 16
    dim3 block(256);
    dim3 grid((batch + rows_per_block - 1) / rows_per_block);
    bidprefix_kernel<<<grid, block, 0, stream>>>(in, out, batch);
}